// Round 7
// baseline (232.722 us; speedup 1.0000x reference)
//
#include <hip/hip_runtime.h>

#define LOG2E 1.4426950408889634f

typedef _Float16 f16x8_t __attribute__((ext_vector_type(8)));
typedef _Float16 f16x4_t __attribute__((ext_vector_type(4)));
typedef _Float16 f16x2_t __attribute__((ext_vector_type(2)));
typedef float    f32x4_t __attribute__((ext_vector_type(4)));

#define MFMA32(a, b, c) __builtin_amdgcn_mfma_f32_16x16x32_f16(a, b, c, 0, 0, 0)
#define MFMA16(a, b, c) __builtin_amdgcn_mfma_f32_16x16x16f16(a, b, c, 0, 0, 0)

// async 16B/lane global->LDS copy. LDS dest is wave-uniform base + lane*16.
__device__ __forceinline__ void async_copy16(void* lds, const void* g) {
    __builtin_amdgcn_global_load_lds(
        (const __attribute__((address_space(1))) unsigned char*)g,
        (__attribute__((address_space(3))) unsigned char*)lds, 16, 0, 0);
}

// ---------------- cast fp32 -> fp16 (vectorized x4) ----------------
__global__ void cast_f32_f16_k(const float* __restrict__ in, _Float16* __restrict__ out, int n4) {
    int i = blockIdx.x * blockDim.x + threadIdx.x;
    if (i >= n4) return;
    float4 v = ((const float4*)in)[i];
    f16x4_t o = { (_Float16)v.x, (_Float16)v.y, (_Float16)v.z, (_Float16)v.w };
    ((f16x4_t*)out)[i] = o;
}

// ---------------- transpose + cast: in [R][C] fp32 -> out [C][R] fp16 ----------------
__global__ void transpose_cast_k(const float* __restrict__ in, _Float16* __restrict__ out,
                                 int R, int C) {
    __shared__ _Float16 tl[64][65];
    const int t = threadIdx.x;
    const int c = t & 63;
    const int r4 = t >> 6;
    const int r0 = blockIdx.y * 64, c0 = blockIdx.x * 64;
#pragma unroll
    for (int i = 0; i < 16; ++i) {
        int r = r4 + i * 4;
        tl[c][r] = (_Float16)in[(size_t)(r0 + r) * C + c0 + c];
    }
    __syncthreads();
#pragma unroll
    for (int i = 0; i < 16; ++i) {
        int rr = r4 + i * 4;
        out[(size_t)(c0 + rr) * R + r0 + c] = tl[rr][c];
    }
}

// ---------------- V^T extraction into pre-baked MFMA tile layout ----------------
// VTg[bh][tile t][d 0..63][cell w 0..7][8 halfs]. Cell (d,w) holds pq=w^(d&7),
// p=pq>>2, q2=pq&3: halfs j0..3 = kv t*64+p*32+q2*4+j, j4..7 = +16.
// Attention lane (ln,qd) reading pair pp then gets its b128 at w=(pp*4+qd)^(ln&7):
// conflict-benign reads AND contiguous global_load_lds staging.
__global__ void vtrans_k(const _Float16* __restrict__ qkv, _Float16* __restrict__ VTg) {
    __shared__ _Float16 tl[64][68];
    const int tid = threadIdx.x;
    const int bh = blockIdx.x;          // b*16+h
    const int b = bh >> 4, h = bh & 15;
    const int t = blockIdx.y;           // kv tile
    const int c = tid & 63;             // d on read
    const int r4 = tid >> 6;
#pragma unroll
    for (int i = 0; i < 16; ++i) {
        int r = r4 + i * 4;             // token offset within tile
        tl[c][r] = qkv[(size_t)(b * 2048 + t * 64 + r) * 3072 + 2048 + h * 64 + c];
    }
    __syncthreads();
    const size_t obase = (size_t)bh * 131072 + (size_t)t * 4096;
#pragma unroll
    for (int e = 0; e < 2; ++e) {
        const int ci = tid * 2 + e;     // cell 0..511
        const int d = ci >> 3, w = ci & 7;
        const int pq = w ^ (d & 7);
        const int base = (pq >> 2) * 32 + (pq & 3) * 4;
        f16x4_t v0 = *(const f16x4_t*)&tl[d][base];
        f16x4_t v1 = *(const f16x4_t*)&tl[d][base + 16];
        f16x8_t val = __builtin_shufflevector(v0, v1, 0, 1, 2, 3, 4, 5, 6, 7);
        *(f16x8_t*)&VTg[obase + ci * 8] = val;
    }
}

// ---------------- GEMM: C[M][N] = A[M][K] * BT[N][K]^T (+bias), fp16 in ----------------
template <typename OutT, bool BIAS>
__global__ __launch_bounds__(256, 2)
void gemm_f16_k(const _Float16* __restrict__ A, const _Float16* __restrict__ BT,
                OutT* __restrict__ C, const float* __restrict__ bias,
                int M, int N, int K) {
    __shared__ _Float16 As[2][128][32];
    __shared__ _Float16 Bs[2][128][32];
    const int tid = threadIdx.x;
    const int wid = tid >> 6, lane = tid & 63;
    const int qd = lane >> 4, ln = lane & 15;
    const int m0 = blockIdx.x * 128, n0 = blockIdx.y * 128;
    const int wm = (wid >> 1) * 64, wn = (wid & 1) * 64;

    f32x4_t acc[4][4] = {};

    const int srow = lane >> 2;
    const int skk  = (lane & 3) * 8;

    for (int k0 = 0; k0 < K; k0 += 64) {
        __syncthreads();
#pragma unroll
        for (int p = 0; p < 4; ++p) {
            const int seg = p * 4 + wid;           // 0..15
            const int s   = seg >> 3;
            const int rg  = seg & 7;
            const int row = rg * 16 + srow;
            const size_t goff = (size_t)row * K + k0 + s * 32 + skk;
            async_copy16(&As[0][0][0] + seg * 512, A  + (size_t)m0 * K + goff);
            async_copy16(&Bs[0][0][0] + seg * 512, BT + (size_t)n0 * K + goff);
        }
        __syncthreads();
#pragma unroll
        for (int s = 0; s < 2; ++s) {
            f16x8_t a[4], b[4];
#pragma unroll
            for (int i = 0; i < 4; ++i)
                a[i] = *(const f16x8_t*)&As[s][wm + i * 16 + ln][qd * 8];
#pragma unroll
            for (int j = 0; j < 4; ++j)
                b[j] = *(const f16x8_t*)&Bs[s][wn + j * 16 + ln][qd * 8];
#pragma unroll
            for (int i = 0; i < 4; ++i)
#pragma unroll
                for (int j = 0; j < 4; ++j)
                    acc[i][j] = MFMA32(a[i], b[j], acc[i][j]);
        }
    }
#pragma unroll
    for (int i = 0; i < 4; ++i)
#pragma unroll
        for (int j = 0; j < 4; ++j) {
            const int col = n0 + wn + j * 16 + ln;
            const float bv = BIAS ? bias[col] : 0.0f;
#pragma unroll
            for (int r = 0; r < 4; ++r) {
                const int row = m0 + wm + i * 16 + qd * 4 + r;
                C[(size_t)row * N + col] = (OutT)(acc[i][j][r] + bv);
            }
        }
}

// ---------------- GEMM 64x128 tile variant (for small-N proj: 2x blocks) ----------------
__global__ __launch_bounds__(256, 2)
void gemm_f16_m64_k(const _Float16* __restrict__ A, const _Float16* __restrict__ BT,
                    float* __restrict__ C, const float* __restrict__ bias,
                    int M, int N, int K) {
    __shared__ _Float16 As[2][64][32];
    __shared__ _Float16 Bs[2][128][32];
    const int tid = threadIdx.x;
    const int wid = tid >> 6, lane = tid & 63;
    const int qd = lane >> 4, ln = lane & 15;
    const int m0 = blockIdx.x * 64, n0 = blockIdx.y * 128;
    const int wn = wid * 32;

    f32x4_t acc[4][2] = {};
    const int srow = lane >> 2;
    const int skk  = (lane & 3) * 8;

    for (int k0 = 0; k0 < K; k0 += 64) {
        __syncthreads();
#pragma unroll
        for (int p = 0; p < 2; ++p) {         // A: 8 segs
            const int seg = p * 4 + wid;
            const int hidx = seg * 512 + lane * 8;
            const int s_ = hidx >> 11;
            const int row = (hidx >> 5) & 63;
            const int kk = hidx & 31;
            async_copy16(&As[0][0][0] + seg * 512,
                         A + (size_t)(m0 + row) * K + k0 + s_ * 32 + kk);
        }
#pragma unroll
        for (int p = 0; p < 4; ++p) {         // B: 16 segs
            const int seg = p * 4 + wid;
            const int s   = seg >> 3;
            const int rg  = seg & 7;
            const int row = rg * 16 + srow;
            async_copy16(&Bs[0][0][0] + seg * 512,
                         BT + (size_t)(n0 + row) * K + k0 + s * 32 + skk);
        }
        __syncthreads();
#pragma unroll
        for (int s = 0; s < 2; ++s) {
            f16x8_t a[4], b[2];
#pragma unroll
            for (int i = 0; i < 4; ++i)
                a[i] = *(const f16x8_t*)&As[s][i * 16 + ln][qd * 8];
#pragma unroll
            for (int j = 0; j < 2; ++j)
                b[j] = *(const f16x8_t*)&Bs[s][wn + j * 16 + ln][qd * 8];
#pragma unroll
            for (int i = 0; i < 4; ++i)
#pragma unroll
                for (int j = 0; j < 2; ++j)
                    acc[i][j] = MFMA32(a[i], b[j], acc[i][j]);
        }
    }
#pragma unroll
    for (int i = 0; i < 4; ++i)
#pragma unroll
        for (int j = 0; j < 2; ++j) {
            const int col = n0 + wn + j * 16 + ln;
            const float bv = bias[col];
#pragma unroll
            for (int r = 0; r < 4; ++r) {
                const int row = m0 + i * 16 + qd * 4 + r;
                C[(size_t)row * N + col] = acc[i][j][r] + bv;
            }
        }
}

// ---------------- per-head LayerNorm on q,k; repack to [b,h,n,d] fp16 ----------------
__global__ void ln_qk_k(const _Float16* __restrict__ qkv, const float* __restrict__ ln_w,
                        const float* __restrict__ ln_b, _Float16* __restrict__ Qb,
                        _Float16* __restrict__ Kb) {
    const int tid = threadIdx.x;
    const int wid = tid >> 6, lane = tid & 63;
    const int row = blockIdx.x * 4 + wid;   // (token, head)
    const int t = row >> 4;
    const int h = row & 15;
    const int b = t >> 11, n = t & 2047;
    const size_t base = (size_t)t * 3072 + h * 64 + lane;
    float q = (float)qkv[base];
    float k = (float)qkv[base + 1024];
    const float wv = ln_w[lane], bv = ln_b[lane];

    float sq = q, sk = k;
#pragma unroll
    for (int m = 1; m < 64; m <<= 1) { sq += __shfl_xor(sq, m); sk += __shfl_xor(sk, m); }
    sq *= (1.0f / 64.0f); sk *= (1.0f / 64.0f);
    const float dq = q - sq, dk = k - sk;
    float vq = dq * dq, vk = dk * dk;
#pragma unroll
    for (int m = 1; m < 64; m <<= 1) { vq += __shfl_xor(vq, m); vk += __shfl_xor(vk, m); }
    vq *= (1.0f / 64.0f); vk *= (1.0f / 64.0f);
    const float yq = dq * rsqrtf(vq + 1e-5f) * wv + bv;
    const float yk = dk * rsqrtf(vk + 1e-5f) * wv + bv;
    const size_t obase = ((size_t)((b * 16 + h) * 2048 + n)) * 64 + lane;
    Qb[obase] = (_Float16)(yq * (8.0f * LOG2E));
    Kb[obase] = (_Float16)yk;
}

// ---------------- flash attention, 32 q-rows/wave, split-KV ----------------
// grid (32 bh, 24 units). Bands of 128 q-rows (0..15). y<16: split bands
// 15-(y>>1), chunk y&1, nst=band+1. y>=16: full bands 7-(y-16), nst=2(band+1).
// 768 blocks, 3/CU, ALL co-resident (VGPR-bound). Block = 4 waves x 32 q-rows
// (2 fragments). Per step each wave reads the 16KB K+V tile once for 32 q-rows
// (2x the prior arithmetic intensity vs LDS). Double-buffered async staging,
// one barrier/step, prefetch issued post-barrier. P^T stays in registers.
__global__ __launch_bounds__(256, 3)
void attn_part_k(const _Float16* __restrict__ Q, const _Float16* __restrict__ K,
                 const _Float16* __restrict__ VTg, _Float16* __restrict__ O,
                 float* __restrict__ Op, float* __restrict__ ml) {
    __shared__ _Float16 Ks[2][2][64][32];   // [buf][plane][kv][k]  16KB
    __shared__ _Float16 VT[2][64][64];      // [buf][d][pre-baked cells] 16KB

    const int tid = threadIdx.x;
    const int wid = tid >> 6, lane = tid & 63;
    const int qd = lane >> 4, ln = lane & 15;
    const int bh = blockIdx.x;
    const int b = bh >> 4, h = bh & 15;
    const int y = blockIdx.y;
    int band, chunk, nst, kvbeg;
    if (y < 16) { band = 15 - (y >> 1); chunk = y & 1; nst = band + 1; kvbeg = chunk * nst * 64; }
    else        { band = 7 - (y - 16);  chunk = -1;    nst = 2 * (band + 1); kvbeg = 0; }
    const size_t kvbase = (size_t)bh * 2048 * 64;
    const size_t vtbase = (size_t)bh * 131072;
    const int qrow0 = band * 128 + wid * 32;

    // Q fragments (MFMA B operand of S^T; q=ln, k spread), 2 frags x 2 k-planes
    f16x8_t qf[2][2];
#pragma unroll
    for (int f = 0; f < 2; ++f)
#pragma unroll
        for (int s = 0; s < 2; ++s)
            qf[f][s] = *(const f16x8_t*)&Q[kvbase + (size_t)(qrow0 + f * 16 + ln) * 64 + s * 32 + qd * 8];

    f32x4_t o[2][4] = {};
    float m[2] = { -3.0e38f, -3.0e38f }, l[2] = { 0.0f, 0.0f };

    auto stage = [&](int buf, int kv0) {
#pragma unroll
        for (int p = 0; p < 2; ++p) {           // K: segs wid*2+p
            const int seg = wid * 2 + p;
            const int hidx = seg * 512 + lane * 8;
            const int s_ = hidx >> 11;
            const int rrow = (hidx >> 5) & 63;
            const int kk = hidx & 31;
            async_copy16(&Ks[buf][0][0][0] + seg * 512,
                         K + kvbase + (size_t)(kv0 + rrow) * 64 + s_ * 32 + kk);
        }
#pragma unroll
        for (int p = 0; p < 2; ++p) {           // V: pre-baked tile, pure linear copy
            const int seg = wid * 2 + p;
            async_copy16(&VT[buf][0][0] + seg * 512,
                         VTg + vtbase + (size_t)kv0 * 64 + seg * 512 + lane * 8);
        }
    };

    stage(0, kvbeg);

    for (int st = 0; st < nst; ++st) {
        const int kv0 = kvbeg + st * 64;
        __syncthreads();                        // drains staging of buf[st&1]
        if (st + 1 < nst) stage((st + 1) & 1, kv0 + 64);
        const int buf = st & 1;

        f16x8_t kb[4][2];
#pragma unroll
        for (int jt = 0; jt < 4; ++jt)
#pragma unroll
            for (int s = 0; s < 2; ++s)
                kb[jt][s] = *(const f16x8_t*)&Ks[buf][s][jt * 16 + ln][qd * 8];
        f16x8_t vf8[4][2];                      // [dt][pp]: b128 from pre-baked cell
#pragma unroll
        for (int dt = 0; dt < 4; ++dt)
#pragma unroll
            for (int pp = 0; pp < 2; ++pp) {
                const int w = (pp * 4 + qd) ^ (ln & 7);
                vf8[dt][pp] = *(const f16x8_t*)&VT[buf][dt * 16 + ln][w * 8];
            }

#pragma unroll
        for (int f = 0; f < 2; ++f) {
            // S^T = K Q^T
            f32x4_t sc[4];
#pragma unroll
            for (int jt = 0; jt < 4; ++jt) {
                f32x4_t s = {};
                s = MFMA32(kb[jt][0], qf[f][0], s);
                s = MFMA32(kb[jt][1], qf[f][1], s);
                sc[jt] = s;
            }
            const int qbase = qrow0 + f * 16;
            if (kv0 + 63 > qbase) {             // (partially) masked step
                const int qq = qbase + ln;
#pragma unroll
                for (int c = 0; c < 4; ++c)
#pragma unroll
                    for (int r = 0; r < 4; ++r)
                        if (kv0 + c * 16 + qd * 4 + r > qq) sc[c][r] = -3.0e38f;
            }
            // online softmax (log2 domain)
            float mx = sc[0][0];
#pragma unroll
            for (int c = 0; c < 4; ++c)
#pragma unroll
                for (int r = 0; r < 4; ++r) mx = fmaxf(mx, sc[c][r]);
            mx = fmaxf(mx, __shfl_xor(mx, 16));
            mx = fmaxf(mx, __shfl_xor(mx, 32));
            const float mn = fmaxf(m[f], mx);
            const float al = exp2f(m[f] - mn);
            m[f] = mn;
            float rs = 0.0f;
            f16x4_t pf[4];
#pragma unroll
            for (int c = 0; c < 4; ++c) {
                float p0 = exp2f(sc[c][0] - mn);
                float p1 = exp2f(sc[c][1] - mn);
                float p2 = exp2f(sc[c][2] - mn);
                float p3 = exp2f(sc[c][3] - mn);
                rs += (p0 + p1) + (p2 + p3);
                f16x2_t a = __builtin_bit_cast(f16x2_t, __builtin_amdgcn_cvt_pkrtz(p0, p1));
                f16x2_t bb = __builtin_bit_cast(f16x2_t, __builtin_amdgcn_cvt_pkrtz(p2, p3));
                pf[c] = __builtin_shufflevector(a, bb, 0, 1, 2, 3);
            }
            l[f] = l[f] * al + rs;
#pragma unroll
            for (int dt = 0; dt < 4; ++dt) o[f][dt] *= al;
#pragma unroll
            for (int dt = 0; dt < 4; ++dt)
#pragma unroll
                for (int pp = 0; pp < 2; ++pp) {
                    f16x4_t lo = __builtin_shufflevector(vf8[dt][pp], vf8[dt][pp], 0, 1, 2, 3);
                    f16x4_t hi = __builtin_shufflevector(vf8[dt][pp], vf8[dt][pp], 4, 5, 6, 7);
                    o[f][dt] = MFMA16(lo, pf[pp * 2 + 0], o[f][dt]);
                    o[f][dt] = MFMA16(hi, pf[pp * 2 + 1], o[f][dt]);
                }
        }
    }

#pragma unroll
    for (int f = 0; f < 2; ++f) {
        float lt = l[f] + __shfl_xor(l[f], 16);
        lt = lt + __shfl_xor(lt, 32);
        if (chunk < 0) {                        // final fp16 output
            const float inv = 1.0f / lt;
            const size_t base = ((size_t)(b * 2048 + qrow0 + f * 16 + ln)) * 1024 + h * 64 + qd * 4;
#pragma unroll
            for (int dt = 0; dt < 4; ++dt) {
                f16x4_t ov;
#pragma unroll
                for (int r = 0; r < 4; ++r) ov[r] = (_Float16)(o[f][dt][r] * inv);
                *(f16x4_t*)&O[base + dt * 16] = ov;
            }
        } else {                                // fp32 partial
            const size_t u = ((size_t)bh * 8 + (band - 8)) * 2 + chunk;
            const int rowi = wid * 32 + f * 16 + ln;
            float* op = Op + u * 8192 + (size_t)rowi * 64 + qd * 4;
#pragma unroll
            for (int dt = 0; dt < 4; ++dt)
                *(f32x4_t*)&op[dt * 16] = o[f][dt];
            if (qd == 0) {
                ml[u * 256 + rowi * 2]     = m[f];
                ml[u * 256 + rowi * 2 + 1] = lt;
            }
        }
    }
}

// ---------------- merge two split-KV partials (bands 8..15) ----------------
__global__ __launch_bounds__(256)
void attn_merge_k(const float* __restrict__ Op, const float* __restrict__ ml,
                  _Float16* __restrict__ O) {
    const int bh = blockIdx.x, sb = blockIdx.y;     // sb 0..7 -> band 8+sb
    const int b = bh >> 4, h = bh & 15;
    const int band = 8 + sb;
    const size_t u = ((size_t)bh * 8 + sb) * 2;
    const int tid = threadIdx.x;
    const int row = tid >> 1;                       // 0..127
    const int d0 = (tid & 1) * 32;
    const float m0 = ml[u * 256 + row * 2],       l0 = ml[u * 256 + row * 2 + 1];
    const float m1 = ml[(u + 1) * 256 + row * 2], l1 = ml[(u + 1) * 256 + row * 2 + 1];
    const float mm = fmaxf(m0, m1);
    const float a0 = exp2f(m0 - mm), a1 = exp2f(m1 - mm);
    const float inv = 1.0f / (l0 * a0 + l1 * a1);
    const float* p0 = Op + u * 8192 + (size_t)row * 64 + d0;
    const float* p1 = p0 + 8192;
    _Float16* op = O + ((size_t)(b * 2048 + band * 128 + row)) * 1024 + h * 64 + d0;
#pragma unroll
    for (int g = 0; g < 8; ++g) {
        f32x4_t v0 = *(const f32x4_t*)&p0[g * 4];
        f32x4_t v1 = *(const f32x4_t*)&p1[g * 4];
        f16x4_t ov;
#pragma unroll
        for (int r = 0; r < 4; ++r)
            ov[r] = (_Float16)((v0[r] * a0 + v1[r] * a1) * inv);
        *(f16x4_t*)&op[g * 4] = ov;
    }
}

extern "C" void kernel_launch(void* const* d_in, const int* in_sizes, int n_in,
                              void* d_out, int out_size, void* d_ws, size_t ws_size,
                              hipStream_t stream) {
    const float* x      = (const float*)d_in[0];
    const float* w_qkv  = (const float*)d_in[1];
    const float* w_proj = (const float*)d_in[2];
    const float* b_proj = (const float*)d_in[3];
    const float* ln_w   = (const float*)d_in[4];
    const float* ln_b   = (const float*)d_in[5];
    float* out = (float*)d_out;

    // workspace partition (~89 MB)
    char* w = (char*)d_ws;
    _Float16*  qkv    = (_Float16*)w;  w += (size_t)4096 * 3072 * 2;    // 24 MB
    _Float16*  xh     = (_Float16*)w;  w += (size_t)4096 * 1024 * 2;    // 8 MB
    _Float16*  wqkvT  = (_Float16*)w;  w += (size_t)3072 * 1024 * 2;    // 6 MB
    _Float16*  wprojT = (_Float16*)w;  w += (size_t)1024 * 1024 * 2;    // 2 MB
    _Float16*  Qb     = (_Float16*)w;  w += (size_t)32 * 2048 * 64 * 2; // 8 MB
    _Float16*  Kb     = (_Float16*)w;  w += (size_t)32 * 2048 * 64 * 2; // 8 MB
    _Float16*  VTg    = (_Float16*)w;  w += (size_t)32 * 64 * 2048 * 2; // 8 MB
    _Float16*  Ah     = (_Float16*)w;  w += (size_t)4096 * 1024 * 2;    // 8 MB
    float*     Op     = (float*)w;     w += (size_t)32 * 8 * 2 * 8192 * 4; // 16 MB
    float*     mlb    = (float*)w;     w += (size_t)32 * 8 * 2 * 256 * 4;  // 0.5 MB

    cast_f32_f16_k<<<4096, 256, 0, stream>>>(x, xh, 4096 * 1024 / 4);
    transpose_cast_k<<<dim3(48, 16), 256, 0, stream>>>(w_qkv, wqkvT, 1024, 3072);
    transpose_cast_k<<<dim3(16, 16), 256, 0, stream>>>(w_proj, wprojT, 1024, 1024);
    gemm_f16_k<_Float16, false><<<dim3(32, 24), 256, 0, stream>>>(xh, wqkvT, qkv, nullptr, 4096, 3072, 1024);
    vtrans_k<<<dim3(32, 32), 256, 0, stream>>>(qkv, VTg);
    ln_qk_k<<<16384, 256, 0, stream>>>(qkv, ln_w, ln_b, Qb, Kb);
    attn_part_k<<<dim3(32, 24), 256, 0, stream>>>(Qb, Kb, VTg, Ah, Op, mlb);
    attn_merge_k<<<dim3(32, 8), 256, 0, stream>>>(Op, mlb, Ah);
    gemm_f16_m64_k<<<dim3(64, 8), 256, 0, stream>>>(Ah, wprojT, out, b_proj, 4096, 1024, 1024);
}

// Round 8
// 207.627 us; speedup vs baseline: 1.1209x; 1.1209x over previous
//
#include <hip/hip_runtime.h>

#define LOG2E 1.4426950408889634f

typedef _Float16 f16x8_t __attribute__((ext_vector_type(8)));
typedef _Float16 f16x4_t __attribute__((ext_vector_type(4)));
typedef _Float16 f16x2_t __attribute__((ext_vector_type(2)));
typedef float    f32x4_t __attribute__((ext_vector_type(4)));

#define MFMA32(a, b, c) __builtin_amdgcn_mfma_f32_16x16x32_f16(a, b, c, 0, 0, 0)
#define MFMA16(a, b, c) __builtin_amdgcn_mfma_f32_16x16x16f16(a, b, c, 0, 0, 0)

// async 16B/lane global->LDS copy. LDS dest is wave-uniform base + lane*16.
__device__ __forceinline__ void async_copy16(void* lds, const void* g) {
    __builtin_amdgcn_global_load_lds(
        (const __attribute__((address_space(1))) unsigned char*)g,
        (__attribute__((address_space(3))) unsigned char*)lds, 16, 0, 0);
}

// ---------------- cast fp32 -> fp16 (vectorized x4) ----------------
__global__ void cast_f32_f16_k(const float* __restrict__ in, _Float16* __restrict__ out, int n4) {
    int i = blockIdx.x * blockDim.x + threadIdx.x;
    if (i >= n4) return;
    float4 v = ((const float4*)in)[i];
    f16x4_t o = { (_Float16)v.x, (_Float16)v.y, (_Float16)v.z, (_Float16)v.w };
    ((f16x4_t*)out)[i] = o;
}

// ---------------- transpose + cast: in [R][C] fp32 -> out [C][R] fp16 ----------------
__global__ void transpose_cast_k(const float* __restrict__ in, _Float16* __restrict__ out,
                                 int R, int C) {
    __shared__ _Float16 tl[64][65];
    const int t = threadIdx.x;
    const int c = t & 63;
    const int r4 = t >> 6;
    const int r0 = blockIdx.y * 64, c0 = blockIdx.x * 64;
#pragma unroll
    for (int i = 0; i < 16; ++i) {
        int r = r4 + i * 4;
        tl[c][r] = (_Float16)in[(size_t)(r0 + r) * C + c0 + c];
    }
    __syncthreads();
#pragma unroll
    for (int i = 0; i < 16; ++i) {
        int rr = r4 + i * 4;
        out[(size_t)(c0 + rr) * R + r0 + c] = tl[rr][c];
    }
}

// ---------------- V^T extraction into pre-baked MFMA tile layout ----------------
// VTg[bh][tile t][d 0..63][cell w 0..7][8 halfs]. Cell (d,w) holds pq=w^(d&7),
// p=pq>>2, q2=pq&3: halfs j0..3 = kv t*64+p*32+q2*4+j, j4..7 = +16.
// Attention lane (ln,qd) reading pair pp gets its b128 at w=(pp*4+qd)^(ln&7):
// conflict-benign reads AND contiguous global_load_lds staging.
__global__ void vtrans_k(const _Float16* __restrict__ qkv, _Float16* __restrict__ VTg) {
    __shared__ _Float16 tl[64][68];
    const int tid = threadIdx.x;
    const int bh = blockIdx.x;          // b*16+h
    const int b = bh >> 4, h = bh & 15;
    const int t = blockIdx.y;           // kv tile
    const int c = tid & 63;             // d on read
    const int r4 = tid >> 6;
#pragma unroll
    for (int i = 0; i < 16; ++i) {
        int r = r4 + i * 4;             // token offset within tile
        tl[c][r] = qkv[(size_t)(b * 2048 + t * 64 + r) * 3072 + 2048 + h * 64 + c];
    }
    __syncthreads();
    const size_t obase = (size_t)bh * 131072 + (size_t)t * 4096;
#pragma unroll
    for (int e = 0; e < 2; ++e) {
        const int ci = tid * 2 + e;     // cell 0..511
        const int d = ci >> 3, w = ci & 7;
        const int pq = w ^ (d & 7);
        const int base = (pq >> 2) * 32 + (pq & 3) * 4;
        f16x4_t v0 = *(const f16x4_t*)&tl[d][base];
        f16x4_t v1 = *(const f16x4_t*)&tl[d][base + 16];
        f16x8_t val = __builtin_shufflevector(v0, v1, 0, 1, 2, 3, 4, 5, 6, 7);
        *(f16x8_t*)&VTg[obase + ci * 8] = val;
    }
}

// ---------------- GEMM: C[M][N] = A[M][K] * BT[N][K]^T (+bias), fp16 in ----------------
// launch_bounds(256,3): 3 blocks/CU so the 768-block QKV GEMM is fully co-resident.
template <typename OutT, bool BIAS>
__global__ __launch_bounds__(256, 3)
void gemm_f16_k(const _Float16* __restrict__ A, const _Float16* __restrict__ BT,
                OutT* __restrict__ C, const float* __restrict__ bias,
                int M, int N, int K) {
    __shared__ _Float16 As[2][128][32];
    __shared__ _Float16 Bs[2][128][32];
    const int tid = threadIdx.x;
    const int wid = tid >> 6, lane = tid & 63;
    const int qd = lane >> 4, ln = lane & 15;
    const int m0 = blockIdx.x * 128, n0 = blockIdx.y * 128;
    const int wm = (wid >> 1) * 64, wn = (wid & 1) * 64;

    f32x4_t acc[4][4] = {};

    const int srow = lane >> 2;
    const int skk  = (lane & 3) * 8;

    for (int k0 = 0; k0 < K; k0 += 64) {
        __syncthreads();
#pragma unroll
        for (int p = 0; p < 4; ++p) {
            const int seg = p * 4 + wid;           // 0..15
            const int s   = seg >> 3;
            const int rg  = seg & 7;
            const int row = rg * 16 + srow;
            const size_t goff = (size_t)row * K + k0 + s * 32 + skk;
            async_copy16(&As[0][0][0] + seg * 512, A  + (size_t)m0 * K + goff);
            async_copy16(&Bs[0][0][0] + seg * 512, BT + (size_t)n0 * K + goff);
        }
        __syncthreads();
#pragma unroll
        for (int s = 0; s < 2; ++s) {
            f16x8_t a[4], b[4];
#pragma unroll
            for (int i = 0; i < 4; ++i)
                a[i] = *(const f16x8_t*)&As[s][wm + i * 16 + ln][qd * 8];
#pragma unroll
            for (int j = 0; j < 4; ++j)
                b[j] = *(const f16x8_t*)&Bs[s][wn + j * 16 + ln][qd * 8];
#pragma unroll
            for (int i = 0; i < 4; ++i)
#pragma unroll
                for (int j = 0; j < 4; ++j)
                    acc[i][j] = MFMA32(a[i], b[j], acc[i][j]);
        }
    }
#pragma unroll
    for (int i = 0; i < 4; ++i)
#pragma unroll
        for (int j = 0; j < 4; ++j) {
            const int col = n0 + wn + j * 16 + ln;
            const float bv = BIAS ? bias[col] : 0.0f;
#pragma unroll
            for (int r = 0; r < 4; ++r) {
                const int row = m0 + wm + i * 16 + qd * 4 + r;
                C[(size_t)row * N + col] = (OutT)(acc[i][j][r] + bv);
            }
        }
}

// ---------------- GEMM 64x128 tile variant (for small-N proj: 2x blocks) ----------------
__global__ __launch_bounds__(256, 2)
void gemm_f16_m64_k(const _Float16* __restrict__ A, const _Float16* __restrict__ BT,
                    float* __restrict__ C, const float* __restrict__ bias,
                    int M, int N, int K) {
    __shared__ _Float16 As[2][64][32];
    __shared__ _Float16 Bs[2][128][32];
    const int tid = threadIdx.x;
    const int wid = tid >> 6, lane = tid & 63;
    const int qd = lane >> 4, ln = lane & 15;
    const int m0 = blockIdx.x * 64, n0 = blockIdx.y * 128;
    const int wn = wid * 32;

    f32x4_t acc[4][2] = {};
    const int srow = lane >> 2;
    const int skk  = (lane & 3) * 8;

    for (int k0 = 0; k0 < K; k0 += 64) {
        __syncthreads();
#pragma unroll
        for (int p = 0; p < 2; ++p) {         // A: 8 segs
            const int seg = p * 4 + wid;
            const int hidx = seg * 512 + lane * 8;
            const int s_ = hidx >> 11;
            const int row = (hidx >> 5) & 63;
            const int kk = hidx & 31;
            async_copy16(&As[0][0][0] + seg * 512,
                         A + (size_t)(m0 + row) * K + k0 + s_ * 32 + kk);
        }
#pragma unroll
        for (int p = 0; p < 4; ++p) {         // B: 16 segs
            const int seg = p * 4 + wid;
            const int s   = seg >> 3;
            const int rg  = seg & 7;
            const int row = rg * 16 + srow;
            async_copy16(&Bs[0][0][0] + seg * 512,
                         BT + (size_t)(n0 + row) * K + k0 + s * 32 + skk);
        }
        __syncthreads();
#pragma unroll
        for (int s = 0; s < 2; ++s) {
            f16x8_t a[4], b[2];
#pragma unroll
            for (int i = 0; i < 4; ++i)
                a[i] = *(const f16x8_t*)&As[s][i * 16 + ln][qd * 8];
#pragma unroll
            for (int j = 0; j < 2; ++j)
                b[j] = *(const f16x8_t*)&Bs[s][wn + j * 16 + ln][qd * 8];
#pragma unroll
            for (int i = 0; i < 4; ++i)
#pragma unroll
                for (int j = 0; j < 2; ++j)
                    acc[i][j] = MFMA32(a[i], b[j], acc[i][j]);
        }
    }
#pragma unroll
    for (int i = 0; i < 4; ++i)
#pragma unroll
        for (int j = 0; j < 2; ++j) {
            const int col = n0 + wn + j * 16 + ln;
            const float bv = bias[col];
#pragma unroll
            for (int r = 0; r < 4; ++r) {
                const int row = m0 + i * 16 + qd * 4 + r;
                C[(size_t)row * N + col] = acc[i][j][r] + bv;
            }
        }
}

// ---------------- per-head LayerNorm on q,k; repack to [b,h,n,d] fp16 ----------------
__global__ void ln_qk_k(const _Float16* __restrict__ qkv, const float* __restrict__ ln_w,
                        const float* __restrict__ ln_b, _Float16* __restrict__ Qb,
                        _Float16* __restrict__ Kb) {
    const int tid = threadIdx.x;
    const int wid = tid >> 6, lane = tid & 63;
    const int row = blockIdx.x * 4 + wid;   // (token, head)
    const int t = row >> 4;
    const int h = row & 15;
    const int b = t >> 11, n = t & 2047;
    const size_t base = (size_t)t * 3072 + h * 64 + lane;
    float q = (float)qkv[base];
    float k = (float)qkv[base + 1024];
    const float wv = ln_w[lane], bv = ln_b[lane];

    float sq = q, sk = k;
#pragma unroll
    for (int m = 1; m < 64; m <<= 1) { sq += __shfl_xor(sq, m); sk += __shfl_xor(sk, m); }
    sq *= (1.0f / 64.0f); sk *= (1.0f / 64.0f);
    const float dq = q - sq, dk = k - sk;
    float vq = dq * dq, vk = dk * dk;
#pragma unroll
    for (int m = 1; m < 64; m <<= 1) { vq += __shfl_xor(vq, m); vk += __shfl_xor(vk, m); }
    vq *= (1.0f / 64.0f); vk *= (1.0f / 64.0f);
    const float yq = dq * rsqrtf(vq + 1e-5f) * wv + bv;
    const float yk = dk * rsqrtf(vk + 1e-5f) * wv + bv;
    const size_t obase = ((size_t)((b * 16 + h) * 2048 + n)) * 64 + lane;
    Qb[obase] = (_Float16)(yq * (8.0f * LOG2E));
    Kb[obase] = (_Float16)yk;
}

// ---------------- flash attention, 16 q-rows/wave, split-KV (round-5 geometry) ----------------
// grid (32 bh, 48 units). Unit y -> (band of 64 q-rows, chunk, nst):
//   y<16 : band=16+y, chunk=0, nst=16     (full 16-step left chunks, biggest first)
//   y<32 : band=47-y, chunk=1, nst=band-15 (diagonal chunks, descending)
//   else : band=47-y, chunk=0, nst=band+1  (single-chunk bands <16, final)
// 1536 blocks. Double-buffered K/V staging (one barrier/step, prefetch issued
// post-barrier). V from pre-baked VTg: linear staging + conflict-benign b128 reads.
// P^T stays in registers (C-layout == B-operand of 16x16x16 MFMA).
__global__ __launch_bounds__(256, 3)
void attn_part_k(const _Float16* __restrict__ Q, const _Float16* __restrict__ K,
                 const _Float16* __restrict__ VTg, _Float16* __restrict__ O,
                 float* __restrict__ Op, float* __restrict__ ml) {
    __shared__ _Float16 Ks[2][2][64][32];   // [buf][plane][kv][k]  16KB
    __shared__ _Float16 VT[2][64][64];      // [buf][d][pre-baked cells] 16KB

    const int tid = threadIdx.x;
    const int wid = tid >> 6, lane = tid & 63;
    const int qd = lane >> 4, ln = lane & 15;
    const int bh = blockIdx.x;
    const int b = bh >> 4, h = bh & 15;
    const int y = blockIdx.y;
    int band, chunk, nst;
    if (y < 16)      { band = 16 + y; chunk = 0; nst = 16; }
    else if (y < 32) { band = 47 - y; chunk = 1; nst = band - 15; }
    else             { band = 47 - y; chunk = 0; nst = band + 1; }
    const size_t kvbase = (size_t)bh * 2048 * 64;
    const size_t vtbase = (size_t)bh * 131072;
    const int qrow0 = band * 64 + wid * 16;
    const int kvbeg = chunk * 1024;

    // Q fragment (MFMA B operand of S^T; q=ln, k spread)
    f16x8_t qf[2];
#pragma unroll
    for (int s = 0; s < 2; ++s)
        qf[s] = *(const f16x8_t*)&Q[kvbase + (size_t)(qrow0 + ln) * 64 + s * 32 + qd * 8];

    f32x4_t o[4] = {};
    float m = -3.0e38f, l = 0.0f;

    auto stage = [&](int buf, int kv0) {
#pragma unroll
        for (int p = 0; p < 2; ++p) {           // K: 8 segs of 1KB
            const int seg = p * 4 + wid;
            const int hidx = seg * 512 + lane * 8;
            const int s_ = hidx >> 11;
            const int rrow = (hidx >> 5) & 63;
            const int kk = hidx & 31;
            async_copy16(&Ks[buf][0][0][0] + seg * 512,
                         K + kvbase + (size_t)(kv0 + rrow) * 64 + s_ * 32 + kk);
        }
#pragma unroll
        for (int p = 0; p < 2; ++p) {           // V: pre-baked tile, pure linear copy
            const int seg = p * 4 + wid;
            async_copy16(&VT[buf][0][0] + seg * 512,
                         VTg + vtbase + (size_t)kv0 * 64 + seg * 512 + lane * 8);
        }
    };

    stage(0, kvbeg);

    for (int st = 0; st < nst; ++st) {
        const int kv0 = kvbeg + st * 64;
        __syncthreads();                        // drains staging of buf[st&1]
        if (st + 1 < nst) stage((st + 1) & 1, kv0 + 64);
        const int buf = st & 1;

        f16x8_t kb[4][2];
#pragma unroll
        for (int jt = 0; jt < 4; ++jt)
#pragma unroll
            for (int s = 0; s < 2; ++s)
                kb[jt][s] = *(const f16x8_t*)&Ks[buf][s][jt * 16 + ln][qd * 8];
        f16x8_t vf8[4][2];                      // [dt][pp]: b128 from pre-baked cell
#pragma unroll
        for (int dt = 0; dt < 4; ++dt)
#pragma unroll
            for (int pp = 0; pp < 2; ++pp) {
                const int w = (pp * 4 + qd) ^ (ln & 7);
                vf8[dt][pp] = *(const f16x8_t*)&VT[buf][dt * 16 + ln][w * 8];
            }

        // S^T = K Q^T
        f32x4_t sc[4];
#pragma unroll
        for (int jt = 0; jt < 4; ++jt) {
            f32x4_t s = {};
            s = MFMA32(kb[jt][0], qf[0], s);
            s = MFMA32(kb[jt][1], qf[1], s);
            sc[jt] = s;
        }
        if (kv0 + 63 > qrow0) {                 // (partially) masked step
            const int qq = qrow0 + ln;
#pragma unroll
            for (int c = 0; c < 4; ++c)
#pragma unroll
                for (int r = 0; r < 4; ++r)
                    if (kv0 + c * 16 + qd * 4 + r > qq) sc[c][r] = -3.0e38f;
        }
        // online softmax (log2 domain)
        float mx = sc[0][0];
#pragma unroll
        for (int c = 0; c < 4; ++c)
#pragma unroll
            for (int r = 0; r < 4; ++r) mx = fmaxf(mx, sc[c][r]);
        mx = fmaxf(mx, __shfl_xor(mx, 16));
        mx = fmaxf(mx, __shfl_xor(mx, 32));
        const float mn = fmaxf(m, mx);
        const float al = exp2f(m - mn);
        m = mn;
        float rs = 0.0f;
        f16x4_t pf[4];
#pragma unroll
        for (int c = 0; c < 4; ++c) {
            float p0 = exp2f(sc[c][0] - mn);
            float p1 = exp2f(sc[c][1] - mn);
            float p2 = exp2f(sc[c][2] - mn);
            float p3 = exp2f(sc[c][3] - mn);
            rs += (p0 + p1) + (p2 + p3);
            f16x2_t a = __builtin_bit_cast(f16x2_t, __builtin_amdgcn_cvt_pkrtz(p0, p1));
            f16x2_t bb = __builtin_bit_cast(f16x2_t, __builtin_amdgcn_cvt_pkrtz(p2, p3));
            pf[c] = __builtin_shufflevector(a, bb, 0, 1, 2, 3);
        }
        l = l * al + rs;
#pragma unroll
        for (int dt = 0; dt < 4; ++dt) o[dt] *= al;
#pragma unroll
        for (int dt = 0; dt < 4; ++dt)
#pragma unroll
            for (int pp = 0; pp < 2; ++pp) {
                f16x4_t lo = __builtin_shufflevector(vf8[dt][pp], vf8[dt][pp], 0, 1, 2, 3);
                f16x4_t hi = __builtin_shufflevector(vf8[dt][pp], vf8[dt][pp], 4, 5, 6, 7);
                o[dt] = MFMA16(lo, pf[pp * 2 + 0], o[dt]);
                o[dt] = MFMA16(hi, pf[pp * 2 + 1], o[dt]);
            }
    }

    // finish row sums across quarters
    float lt = l + __shfl_xor(l, 16);
    lt = lt + __shfl_xor(lt, 32);

    if (band < 16) {                            // final output
        const float inv = 1.0f / lt;
        const size_t base = ((size_t)(b * 2048 + qrow0 + ln)) * 1024 + h * 64 + qd * 4;
#pragma unroll
        for (int dt = 0; dt < 4; ++dt) {
            f16x4_t ov;
#pragma unroll
            for (int r = 0; r < 4; ++r) ov[r] = (_Float16)(o[dt][r] * inv);
            *(f16x4_t*)&O[base + dt * 16] = ov;
        }
    } else {                                    // fp32 partial
        const size_t pb = (((size_t)bh * 16 + (band - 16)) * 2 + chunk);
        const int row = wid * 16 + ln;
        float* op = Op + pb * 4096 + (size_t)row * 64 + qd * 4;
#pragma unroll
        for (int dt = 0; dt < 4; ++dt)
            *(f32x4_t*)&op[dt * 16] = o[dt];
        if (qd == 0) {
            ml[pb * 128 + row * 2]     = m;
            ml[pb * 128 + row * 2 + 1] = lt;
        }
    }
}

// ---------------- merge two split-KV partials (bands 16..31) ----------------
__global__ __launch_bounds__(256)
void attn_merge_k(const float* __restrict__ Op, const float* __restrict__ ml,
                  _Float16* __restrict__ O) {
    const int bh = blockIdx.x, bnd = blockIdx.y;    // bnd 0..15 -> band 16+bnd
    const int b = bh >> 4, h = bh & 15;
    const int band = 16 + bnd;
    const size_t pb = ((size_t)bh * 16 + bnd) * 2;
    const int tid = threadIdx.x;
    const int row = tid >> 2;
    const int c4 = (tid & 3) * 16;
    const float m0 = ml[pb * 128 + row * 2],     l0 = ml[pb * 128 + row * 2 + 1];
    const float m1 = ml[pb * 128 + 128 + row * 2], l1 = ml[pb * 128 + 128 + row * 2 + 1];
    const float mm = fmaxf(m0, m1);
    const float a0 = exp2f(m0 - mm), a1 = exp2f(m1 - mm);
    const float inv = 1.0f / (l0 * a0 + l1 * a1);
    const float* p0 = Op + pb * 4096 + (size_t)row * 64 + c4;
    const float* p1 = p0 + 4096;
    _Float16* op = O + ((size_t)(b * 2048 + band * 64 + row)) * 1024 + h * 64 + c4;
#pragma unroll
    for (int g = 0; g < 4; ++g) {
        f32x4_t v0 = *(const f32x4_t*)&p0[g * 4];
        f32x4_t v1 = *(const f32x4_t*)&p1[g * 4];
        f16x4_t ov;
#pragma unroll
        for (int r = 0; r < 4; ++r)
            ov[r] = (_Float16)((v0[r] * a0 + v1[r] * a1) * inv);
        *(f16x4_t*)&op[g * 4] = ov;
    }
}

extern "C" void kernel_launch(void* const* d_in, const int* in_sizes, int n_in,
                              void* d_out, int out_size, void* d_ws, size_t ws_size,
                              hipStream_t stream) {
    const float* x      = (const float*)d_in[0];
    const float* w_qkv  = (const float*)d_in[1];
    const float* w_proj = (const float*)d_in[2];
    const float* b_proj = (const float*)d_in[3];
    const float* ln_w   = (const float*)d_in[4];
    const float* ln_b   = (const float*)d_in[5];
    float* out = (float*)d_out;

    // workspace partition (~89 MB)
    char* w = (char*)d_ws;
    _Float16*  qkv    = (_Float16*)w;  w += (size_t)4096 * 3072 * 2;    // 24 MB
    _Float16*  xh     = (_Float16*)w;  w += (size_t)4096 * 1024 * 2;    // 8 MB
    _Float16*  wqkvT  = (_Float16*)w;  w += (size_t)3072 * 1024 * 2;    // 6 MB
    _Float16*  wprojT = (_Float16*)w;  w += (size_t)1024 * 1024 * 2;    // 2 MB
    _Float16*  Qb     = (_Float16*)w;  w += (size_t)32 * 2048 * 64 * 2; // 8 MB
    _Float16*  Kb     = (_Float16*)w;  w += (size_t)32 * 2048 * 64 * 2; // 8 MB
    _Float16*  VTg    = (_Float16*)w;  w += (size_t)32 * 64 * 2048 * 2; // 8 MB
    _Float16*  Ah     = (_Float16*)w;  w += (size_t)4096 * 1024 * 2;    // 8 MB
    float*     Op     = (float*)w;     w += (size_t)32 * 16 * 2 * 4096 * 4; // 16 MB
    float*     mlb    = (float*)w;     w += (size_t)32 * 16 * 2 * 128 * 4;  // 0.5 MB

    cast_f32_f16_k<<<4096, 256, 0, stream>>>(x, xh, 4096 * 1024 / 4);
    transpose_cast_k<<<dim3(48, 16), 256, 0, stream>>>(w_qkv, wqkvT, 1024, 3072);
    transpose_cast_k<<<dim3(16, 16), 256, 0, stream>>>(w_proj, wprojT, 1024, 1024);
    gemm_f16_k<_Float16, false><<<dim3(32, 24), 256, 0, stream>>>(xh, wqkvT, qkv, nullptr, 4096, 3072, 1024);
    vtrans_k<<<dim3(32, 32), 256, 0, stream>>>(qkv, VTg);
    ln_qk_k<<<16384, 256, 0, stream>>>(qkv, ln_w, ln_b, Qb, Kb);
    attn_part_k<<<dim3(32, 48), 256, 0, stream>>>(Qb, Kb, VTg, Ah, Op, mlb);
    attn_merge_k<<<dim3(32, 16), 256, 0, stream>>>(Op, mlb, Ah);
    gemm_f16_m64_k<<<dim3(64, 8), 256, 0, stream>>>(Ah, wprojT, out, b_proj, 4096, 1024, 1024);
}